// Round 13
// baseline (427.677 us; speedup 1.0000x reference)
//
#include <hip/hip_runtime.h>

#define NN 50000
#define NE 800000
#define NG 64
#define EPSF 1e-5f

typedef __bf16 bf16x8 __attribute__((ext_vector_type(8)));
typedef float f32x4 __attribute__((ext_vector_type(4)));

#define AS1 __attribute__((address_space(1)))
#define AS3 __attribute__((address_space(3)))

__device__ __forceinline__ void gl_lds16(const unsigned short* g, unsigned short* l) {
#if __has_builtin(__builtin_amdgcn_global_load_lds)
  __builtin_amdgcn_global_load_lds((const AS1 void*)g, (AS3 void*)l, 16, 0, 0);
#else
  *(uint4*)l = *(const uint4*)g;
#endif
}

__device__ __forceinline__ unsigned short f2bf(float f) {
  unsigned u = __builtin_bit_cast(unsigned, f);
  u += 0x7fff + ((u >> 16) & 1);  // RNE
  return (unsigned short)(u >> 16);
}
__device__ __forceinline__ float bf_lo(unsigned u) {
  return __builtin_bit_cast(float, u << 16);
}
__device__ __forceinline__ float bf_hi(unsigned u) {
  return __builtin_bit_cast(float, u & 0xffff0000u);
}

// ---------------- fused prep: u8 single-pass LDS hist | x->bf16 | weights->bf16^T --------
#define NB_H 64
#define EC   12500        // NE / NB_H
#define HWORDS 12500      // 50000 bins / 4 per word
#define XB   1563         // ceil(NN*128/4 / 1024)
#define XTOT 1600000      // NN*128/4
#define WTB  256          // 262144/1024
__global__ __launch_bounds__(1024) void prep_kernel(
    const int* __restrict__ src, const int* __restrict__ dst,
    unsigned char* __restrict__ hout, unsigned char* __restrict__ hin,
    int* __restrict__ rank,
    const float* __restrict__ x, unsigned short* __restrict__ xb,
    const float* __restrict__ W1, const float* __restrict__ Wfc,
    const float* __restrict__ W2, const float* __restrict__ W3,
    unsigned short* __restrict__ W1t, unsigned short* __restrict__ Wfct,
    unsigned short* __restrict__ W2t, unsigned short* __restrict__ W3t) {
  __shared__ unsigned hist[HWORDS];  // 50 KB
  int b = blockIdx.x;
  int tid = threadIdx.x;
  if (b < NB_H) {
    int e0 = b * EC;
#pragma unroll
    for (int ph = 0; ph < 2; ph++) {
      const int* key = ph ? src : dst;
      unsigned char* gh = (ph ? hout : hin) + (size_t)b * NN;
      for (int i = tid; i < HWORDS; i += 1024) hist[i] = 0u;
      __syncthreads();
      for (int i = tid; i < EC; i += 1024) {
        int k = key[e0 + i];
        int sh = (k & 3) << 3;
        unsigned old = atomicAdd(&hist[k >> 2], 1u << sh);
        if (ph == 0) rank[e0 + i] = (int)((old >> sh) & 0xffu);
      }
      __syncthreads();
      unsigned* gw = (unsigned*)gh;  // b*NN is 4-aligned (NN%4==0)
      for (int i = tid; i < HWORDS; i += 1024) gw[i] = hist[i];
      __syncthreads();
    }
  } else if (b < NB_H + XB) {
    int i = (b - NB_H) * 1024 + tid;
    if (i < XTOT) {
      float4 v = ((const float4*)x)[i];
      uint2 pk;
      pk.x = (unsigned)f2bf(v.x) | ((unsigned)f2bf(v.y) << 16);
      pk.y = (unsigned)f2bf(v.z) | ((unsigned)f2bf(v.w) << 16);
      ((uint2*)xb)[i] = pk;
    }
  } else {
    int i = (b - NB_H - XB) * 1024 + tid;  // 0..262143
    const float* W; unsigned short* Wt; int K, local;
    if (i < 32768)       { W = W1;  Wt = W1t;  K = 128; local = i; }
    else if (i < 65536)  { W = Wfc; Wt = Wfct; K = 128; local = i - 32768; }
    else if (i < 196608) { W = W2;  Wt = W2t;  K = 512; local = i - 65536; }
    else                 { W = W3;  Wt = W3t;  K = 256; local = i - 196608; }
    int n = local / K, k = local - n * K;
    Wt[local] = f2bf(W[(size_t)k * 256 + n]);
  }
}

// ---------------- norms + cross-block hist reduce/prefix + scan phase 1 ----------------
__global__ void norms_scan1(const unsigned char* __restrict__ hout,
                            unsigned char* __restrict__ hin,   // becomes binBase in place
                            int* __restrict__ din,
                            float* __restrict__ onorm, float* __restrict__ inorm,
                            int* __restrict__ bsum, int n) {
  int i = blockIdx.x * 256 + threadIdx.x;
  int d = 0;
  if (i < n) {
    int a = 0;
    for (int b = 0; b < NB_H; b++) a += hout[(size_t)b * NN + i];
    int run = 0;
    for (int b = 0; b < NB_H; b++) {  // in-place exclusive prefix over blocks
      int t = hin[(size_t)b * NN + i];
      hin[(size_t)b * NN + i] = (unsigned char)run;
      run += t;
    }
    d = run;
    din[i] = run;
    onorm[i] = rsqrtf((float)(a > 1 ? a : 1));
    inorm[i] = rsqrtf((float)(d > 1 ? d : 1));
  }
  int v = d;
#pragma unroll
  for (int off = 32; off > 0; off >>= 1) v += __shfl_down(v, off);
  __shared__ int ws[4];
  int wave = threadIdx.x >> 6, lane = threadIdx.x & 63;
  if (lane == 0) ws[wave] = v;
  __syncthreads();
  if (threadIdx.x == 0) bsum[blockIdx.x] = ws[0] + ws[1] + ws[2] + ws[3];
}

// ---------------- scan phase 2+3 fused: each block redundantly scans bsum ----------------
__global__ void scan3_kernel(const int* __restrict__ din, const int* __restrict__ bsum,
                             int* __restrict__ rp, int n, int nb) {
  int t = threadIdx.x;
  int lane = t & 63, wave = t >> 6;
  int bj = (t < nb) ? bsum[t] : 0;
  int pre = (t < (int)blockIdx.x) ? bj : 0;
  int p = pre, q = bj;
#pragma unroll
  for (int off = 32; off > 0; off >>= 1) {
    p += __shfl_down(p, off);
    q += __shfl_down(q, off);
  }
  __shared__ int red[8];
  __shared__ int baseS, totS;
  if (lane == 0) { red[wave] = p; red[4 + wave] = q; }
  __syncthreads();
  if (t == 0) {
    baseS = red[0] + red[1] + red[2] + red[3];
    totS  = red[4] + red[5] + red[6] + red[7];
  }
  __syncthreads();
  int i = blockIdx.x * 256 + t;
  int v = (i < n) ? din[i] : 0;
  __shared__ int tmp[256];
  tmp[t] = v;
  __syncthreads();
  for (int off = 1; off < 256; off <<= 1) {
    int x = (t >= off) ? tmp[t - off] : 0;
    __syncthreads();
    tmp[t] += x;
    __syncthreads();
  }
  if (i < n) rp[i] = tmp[t] - v + baseS;
  if (blockIdx.x == gridDim.x - 1 && t == 0) rp[n] = totS;
}

// ---------------- CSR fill, atomic-free; edge = {col, wse} interleaved ----------------
__global__ void fill_kernel(const int* __restrict__ src, const int* __restrict__ dst,
                            const float* __restrict__ w, const float* __restrict__ onorm,
                            const float* __restrict__ inorm,
                            const int* __restrict__ rp, const int* __restrict__ rank,
                            const unsigned char* __restrict__ binBase,
                            uint2* __restrict__ edge, int E) {
  int e = blockIdx.x * 256 + threadIdx.x;
  if (e < E) {
    int d = dst[e], s = src[e];
    int b = e / EC;  // histogram chunk that counted this edge
    int pos = rp[d] + (int)binBase[(size_t)b * NN + d] + rank[e];
    float wv = w[e] * onorm[s] * inorm[d];
    edge[pos] = make_uint2((unsigned)s, __builtin_bit_cast(unsigned, wv));
  }
}

// ---------------- SpMM (interleaved edges, 8-edge unroll) ----------------
template <int RELU, int NU>
__global__ __launch_bounds__(64) void spmm_bf16(
    const unsigned short* __restrict__ feat, int ldf,
    const int* __restrict__ rp, const uint2* __restrict__ edge,
    unsigned short* __restrict__ out, int ldo) {
  int v = blockIdx.x;
  int t = threadIdx.x;  // 64
  int beg = rp[v], end = rp[v + 1];
  float acc[2 * NU];
#pragma unroll
  for (int i = 0; i < 2 * NU; i++) acc[i] = 0.f;
  const unsigned short* base = feat + t * (2 * NU);
  int e = beg;
  for (; e + 8 <= end; e += 8) {
    int s[8]; float ww[8];
#pragma unroll
    for (int k = 0; k < 8; k++) {
      uint2 q = edge[e + k];
      s[k] = (int)q.x;
      ww[k] = __builtin_bit_cast(float, q.y);
    }
    unsigned u[8][NU];
#pragma unroll
    for (int k = 0; k < 8; k++) {
      const unsigned* pr = (const unsigned*)&base[(size_t)s[k] * ldf];
      if (NU == 2) { uint2 q = *(const uint2*)pr; u[k][0] = q.x; u[k][NU - 1] = q.y; }
      else u[k][0] = pr[0];
    }
#pragma unroll
    for (int k = 0; k < 8; k++)
#pragma unroll
      for (int j = 0; j < NU; j++) {
        acc[2 * j]     += ww[k] * bf_lo(u[k][j]);
        acc[2 * j + 1] += ww[k] * bf_hi(u[k][j]);
      }
  }
  for (; e < end; e++) {
    uint2 qe = edge[e];
    float w0 = __builtin_bit_cast(float, qe.y);
    const unsigned* pr = (const unsigned*)&base[(size_t)qe.x * ldf];
    unsigned u[NU];
    if (NU == 2) { uint2 q = *(const uint2*)pr; u[0] = q.x; u[NU - 1] = q.y; }
    else u[0] = pr[0];
#pragma unroll
    for (int j = 0; j < NU; j++) {
      acc[2 * j]     += w0 * bf_lo(u[j]);
      acc[2 * j + 1] += w0 * bf_hi(u[j]);
    }
  }
  unsigned o[NU];
#pragma unroll
  for (int j = 0; j < NU; j++) {
    float a = acc[2 * j], b = acc[2 * j + 1];
    if (RELU) { a = fmaxf(a, 0.f); b = fmaxf(b, 0.f); }
    o[j] = (unsigned)f2bf(a) | ((unsigned)f2bf(b) << 16);
  }
  unsigned* po = (unsigned*)&out[(size_t)v * ldo + t * (2 * NU)];
  if (NU == 2) *(uint2*)po = make_uint2(o[0], o[NU - 1]);
  else po[0] = o[0];
}

// ---------------- MFMA GEMM core: 128x128 tile, BK=64, double-buffered (R5-proven) ------
__device__ __forceinline__ void gemm_core(
    const unsigned short* __restrict__ A, int lda,
    const unsigned short* __restrict__ Bt, int K, int M,
    int bm, int bn, int relu,
    unsigned short (*As)[8192], unsigned short (*Bs)[8192],
    f32x4 (&acc)[4][4]) {
  const int tid = threadIdx.x;
  const int lane = tid & 63;
  const int m0 = bm * 128;
  const int n0 = bn * 128;

#pragma unroll
  for (int i = 0; i < 4; i++)
#pragma unroll
    for (int j = 0; j < 4; j++) acc[i][j] = (f32x4){0.f, 0.f, 0.f, 0.f};

  const unsigned short* pa[4];
  const unsigned short* pb[4];
#pragma unroll
  for (int i = 0; i < 4; i++) {
    int ch = i * 256 + tid;
    int sub = ch >> 6, sl = ch & 63;
    int mi = sub >> 1, kk = sub & 1;
    int row = mi * 16 + (sl & 15);
    int kc = kk * 32 + (sl >> 4) * 8;
    int gm = m0 + row; if (gm >= M) gm = M - 1;
    pa[i] = A + (size_t)gm * lda + kc;
    int gn = n0 + row;
    pb[i] = Bt + (size_t)gn * K + kc;
  }

  const int NT = K >> 6;
#pragma unroll
  for (int i = 0; i < 4; i++) {
    int ch8 = (i * 256 + tid) * 8;
    gl_lds16(pa[i], &As[0][ch8]);
    gl_lds16(pb[i], &Bs[0][ch8]);
  }
  __syncthreads();

  const int wv = tid >> 6;
  const int wm = wv >> 1, wn = wv & 1;
  int cur = 0;
  for (int t = 0; t < NT; t++) {
    if (t + 1 < NT) {
      int nk = (t + 1) << 6;
#pragma unroll
      for (int i = 0; i < 4; i++) {
        int ch8 = (i * 256 + tid) * 8;
        gl_lds16(pa[i] + nk, &As[cur ^ 1][ch8]);
        gl_lds16(pb[i] + nk, &Bs[cur ^ 1][ch8]);
      }
    }
#pragma unroll
    for (int kk = 0; kk < 2; kk++) {
      bf16x8 af[4], bfr[4];
#pragma unroll
      for (int i = 0; i < 4; i++)
        af[i] = *(const bf16x8*)&As[cur][((wm * 4 + i) * 2 + kk) * 512 + lane * 8];
#pragma unroll
      for (int j = 0; j < 4; j++)
        bfr[j] = *(const bf16x8*)&Bs[cur][((wn * 4 + j) * 2 + kk) * 512 + lane * 8];
#pragma unroll
      for (int i = 0; i < 4; i++)
#pragma unroll
        for (int j = 0; j < 4; j++)
          acc[i][j] = __builtin_amdgcn_mfma_f32_16x16x32_bf16(af[i], bfr[j], acc[i][j], 0, 0, 0);
    }
    __syncthreads();
    cur ^= 1;
  }
  if (relu) {
#pragma unroll
    for (int i = 0; i < 4; i++)
#pragma unroll
      for (int j = 0; j < 4; j++)
#pragma unroll
        for (int r = 0; r < 4; r++) acc[i][j][r] = fmaxf(acc[i][j][r], 0.f);
  }
}

__device__ __forceinline__ void gemm_store(
    const f32x4 (&acc)[4][4], unsigned short* __restrict__ C, int ldc,
    int col_off, int M, int bm, int bn) {
  const int tid = threadIdx.x;
  const int lane = tid & 63;
  const int wv = tid >> 6;
  const int wm = wv >> 1, wn = wv & 1;
  const int q = lane >> 4, r16 = lane & 15;
  const int m0 = bm * 128, n0 = bn * 128;
#pragma unroll
  for (int i = 0; i < 4; i++) {
    int rbase = m0 + wm * 64 + i * 16 + q * 4;
#pragma unroll
    for (int r = 0; r < 4; r++) {
      int gm = rbase + r;
      if (gm >= M) continue;
#pragma unroll
      for (int j = 0; j < 4; j++) {
        int gn = col_off + n0 + wn * 64 + j * 16 + r16;
        C[(size_t)gm * ldc + gn] = f2bf(acc[i][j][r]);
      }
    }
  }
}

// ---------------- fc GEMM (64x256, K=128 single tile) + LayerNorm + relu epilogue --------
__device__ __forceinline__ void fcln_body(
    const unsigned short* __restrict__ A, const unsigned short* __restrict__ Bt,
    const float* __restrict__ gamma, const float* __restrict__ beta,
    unsigned short* __restrict__ C, int M, unsigned short* lds) {
  const int tid = threadIdx.x;
  const int lane = tid & 63;
  const int w = tid >> 6;
  const int q = lane >> 4, r16 = lane & 15;
  const int m0 = blockIdx.x * 64;
  unsigned short* As = lds;          // 16 subtiles * 512 shorts (A 64x128)
  unsigned short* Bs = lds + 8192;   // 64 subtiles * 512 shorts (B^T 256x128)

#pragma unroll
  for (int i = 0; i < 4; i++) {
    int ch = i * 256 + tid;
    int st = ch >> 6, sl = ch & 63;
    int mi = st >> 2, kk = st & 3;
    int gm = m0 + mi * 16 + (sl & 15); if (gm >= M) gm = M - 1;
    int k = kk * 32 + (sl >> 4) * 8;
    gl_lds16(A + (size_t)gm * 128 + k, &As[ch * 8]);
  }
#pragma unroll
  for (int i = 0; i < 16; i++) {
    int ch = i * 256 + tid;
    int st = ch >> 6, sl = ch & 63;
    int ns = st >> 2, kk = st & 3;
    int n = ns * 16 + (sl & 15);
    int k = kk * 32 + (sl >> 4) * 8;
    gl_lds16(Bt + (size_t)n * 128 + k, &Bs[ch * 8]);
  }
  __syncthreads();

  f32x4 acc[4][4];
#pragma unroll
  for (int i = 0; i < 4; i++)
#pragma unroll
    for (int j = 0; j < 4; j++) acc[i][j] = (f32x4){0.f, 0.f, 0.f, 0.f};

#pragma unroll
  for (int kk = 0; kk < 4; kk++) {
    bf16x8 af[4], bfr[4];
#pragma unroll
    for (int i = 0; i < 4; i++)
      af[i] = *(const bf16x8*)&As[(i * 4 + kk) * 512 + lane * 8];
#pragma unroll
    for (int j = 0; j < 4; j++)
      bfr[j] = *(const bf16x8*)&Bs[((w * 4 + j) * 4 + kk) * 512 + lane * 8];
#pragma unroll
    for (int i = 0; i < 4; i++)
#pragma unroll
      for (int j = 0; j < 4; j++)
        acc[i][j] = __builtin_amdgcn_mfma_f32_16x16x32_bf16(af[i], bfr[j], acc[i][j], 0, 0, 0);
  }
  __syncthreads();  // LDS now reusable for reduction

  float* fws = (float*)lds;       // [4][64] wave partial sums
  float* fwq = fws + 256;         // [4][64] wave partial sumsq
  float* fmean = fwq + 256;       // [64]
  float* frs = fmean + 64;        // [64]

#pragma unroll
  for (int i = 0; i < 4; i++)
#pragma unroll
    for (int r = 0; r < 4; r++) {
      float s  = acc[i][0][r] + acc[i][1][r] + acc[i][2][r] + acc[i][3][r];
      float q2 = acc[i][0][r] * acc[i][0][r] + acc[i][1][r] * acc[i][1][r] +
                 acc[i][2][r] * acc[i][2][r] + acc[i][3][r] * acc[i][3][r];
#pragma unroll
      for (int off = 8; off > 0; off >>= 1) {
        s  += __shfl_down(s, off, 16);
        q2 += __shfl_down(q2, off, 16);
      }
      if (r16 == 0) {
        int row = i * 16 + q * 4 + r;
        fws[w * 64 + row] = s;
        fwq[w * 64 + row] = q2;
      }
    }
  __syncthreads();
  if (tid < 64) {
    float S = fws[tid] + fws[64 + tid] + fws[128 + tid] + fws[192 + tid];
    float Q = fwq[tid] + fwq[64 + tid] + fwq[128 + tid] + fwq[192 + tid];
    float mean = S * (1.f / 256.f);
    float var = Q * (1.f / 256.f) - mean * mean;
    fmean[tid] = mean;
    frs[tid] = rsqrtf(var + EPSF);
  }
  __syncthreads();

  float g4[4], b4[4];
#pragma unroll
  for (int j = 0; j < 4; j++) {
    int c = w * 64 + j * 16 + r16;
    g4[j] = gamma[c];
    b4[j] = beta[c];
  }
#pragma unroll
  for (int i = 0; i < 4; i++)
#pragma unroll
    for (int r = 0; r < 4; r++) {
      int row = i * 16 + q * 4 + r;
      int gm = m0 + row;
      if (gm >= M) continue;
      float mean = fmean[row], rs = frs[row];
#pragma unroll
      for (int j = 0; j < 4; j++) {
        int c = w * 64 + j * 16 + r16;
        float y = (acc[i][j][r] - mean) * rs * g4[j] + b4[j];
        C[(size_t)gm * 512 + 256 + c] = f2bf(fmaxf(y, 0.f));
      }
    }
}

// z=0: x1 = relu(aggX@W1) -> x1f1[:,0:256] (128x128 tiles, bm=bx>>1, bn=bx&1)
// z=1: f1 = relu(LN(xb@Wfc)) -> x1f1[:,256:512] (64x256 tiles, m0=bx*64)
__global__ __launch_bounds__(256) void g12f_kernel(
    const unsigned short* __restrict__ A0, const unsigned short* __restrict__ B0,
    const unsigned short* __restrict__ A1, const unsigned short* __restrict__ B1,
    const float* __restrict__ gamma, const float* __restrict__ beta,
    unsigned short* __restrict__ C, int M) {
  __shared__ unsigned short lds[40960];  // 80 KB
  if (blockIdx.z == 0) {
    f32x4 acc[4][4];
    int bm = blockIdx.x >> 1, bn = blockIdx.x & 1;
    gemm_core(A0, 128, B0, 128, M, bm, bn, 1,
              (unsigned short (*)[8192])lds,
              (unsigned short (*)[8192])(lds + 16384), acc);
    gemm_store(acc, C, 512, 0, M, bm, bn);
  } else {
    fcln_body(A1, B1, gamma, beta, C, M, lds);
  }
}

// generic GEMM (y2 = x1f1 @ W2)
__global__ __launch_bounds__(256) void gemm_kernel(
    const unsigned short* __restrict__ A, int lda,
    const unsigned short* __restrict__ Bt, int K,
    unsigned short* __restrict__ C, int ldc, int M, int relu) {
  __shared__ unsigned short As[2][8192];
  __shared__ unsigned short Bs[2][8192];
  f32x4 acc[4][4];
  gemm_core(A, lda, Bt, K, M, blockIdx.x, blockIdx.y, relu, As, Bs, acc);
  gemm_store(acc, C, ldc, 0, M, blockIdx.x, blockIdx.y);
}

// ---------------- x3 GEMM + readout: fcln-style single-shot LDS staging ----------------
// R12 postmortem: compiler refuses to hold direct-from-global MFMA operands in VGPRs
// (VGPR=48, MLP~1 -> the 64us constant). The proven-fast pattern is gl_lds staging
// (deep queue MLP) + ds_read fragments (fcln_body never tops profile). Block = 64 nodes
// x 64 cols (grid 782x4); stage A 32KB + B 32KB; wave = 16 nodes, 4 coltiles x 8 MFMA.
__global__ __launch_bounds__(256) void gemm_ro3(
    const unsigned short* __restrict__ A,    // aggx2 [NN][256]
    const unsigned short* __restrict__ Bt,   // W3t [256][256]
    const int* __restrict__ gid, float* __restrict__ part, int M) {
  __shared__ unsigned short As[32 * 512];  // 64 rows x 256 K (32 KB), subtile-lane order
  __shared__ unsigned short Bs[32 * 512];  // 64 cols x 256 K (32 KB)
  __shared__ float red[4][64];
  const int tid = threadIdx.x;
  const int l = tid & 63;
  const int w = tid >> 6;
  const int v0 = blockIdx.x * 64;
  const int n0 = blockIdx.y * 64;

  // stage A: 2048 chunks of 8 shorts (8/thread); subtile st = i*8+kt (i=rowtile, kt=ktile)
#pragma unroll
  for (int i = 0; i < 8; i++) {
    int ch = i * 256 + tid;
    int st = ch >> 6, sl = ch & 63;
    int rt = st >> 3, kt = st & 7;
    int gm = v0 + rt * 16 + (sl & 15); if (gm >= M) gm = M - 1;
    int k = kt * 32 + (sl >> 4) * 8;
    gl_lds16(A + (size_t)gm * 256 + k, &As[ch * 8]);
  }
  // stage B: same layout over output cols
#pragma unroll
  for (int i = 0; i < 8; i++) {
    int ch = i * 256 + tid;
    int st = ch >> 6, sl = ch & 63;
    int ct = st >> 3, kt = st & 7;
    int row = n0 + ct * 16 + (sl & 15);  // Bt row = output col
    int k = kt * 32 + (sl >> 4) * 8;
    gl_lds16(Bt + (size_t)row * 256 + k, &Bs[ch * 8]);
  }
  for (int i = tid; i < 256; i += 256) ((float*)red)[i] = 0.f;
  __syncthreads();

  const int r16 = l & 15, q = l >> 4;
  const int vw = v0 + w * 16;  // wave's 16 nodes (rowtile w)
  int g0 = gid[v0];
  int slot[4];
#pragma unroll
  for (int j = 0; j < 4; j++) {
    int gm = vw + q * 4 + j;
    slot[j] = (gm < M) ? gid[gm] - g0 : -1;
  }

  bf16x8 af[8];
#pragma unroll
  for (int kt = 0; kt < 8; kt++)
    af[kt] = *(const bf16x8*)&As[(w * 8 + kt) * 512 + l * 8];

#pragma unroll
  for (int ct = 0; ct < 4; ct++) {
    f32x4 acc = (f32x4){0.f, 0.f, 0.f, 0.f};
#pragma unroll
    for (int kt = 0; kt < 8; kt++) {
      bf16x8 bf = *(const bf16x8*)&Bs[(ct * 8 + kt) * 512 + l * 8];
      acc = __builtin_amdgcn_mfma_f32_16x16x32_bf16(af[kt], bf, acc, 0, 0, 0);
    }
    int col = ct * 16 + r16;  // within the 64-col block
#pragma unroll
    for (int j = 0; j < 4; j++) {
      float vv = fmaxf(acc[j], 0.f);
      int sl = slot[j];
      if ((unsigned)sl < 4u && vv != 0.f) atomicAdd(&red[sl][col], vv);
    }
  }
  __syncthreads();
  // part layout: [bx][by][slot][64]
  float* pp = part + ((size_t)(blockIdx.x * 4 + blockIdx.y) * 4) * 64;
  for (int i = tid; i < 256; i += 256) pp[i] = ((float*)red)[i];
}

// out[g][c] = sum of partials from blocks covering graph g (deterministic, no atomics)
__global__ void readout_reduce(const float* __restrict__ part,
                               const int* __restrict__ gid,
                               float* __restrict__ out, int n) {
  int g = blockIdx.x;   // 64
  int c = threadIdx.x;  // 256
  int lo = 0, hi = n;
  while (lo < hi) { int mid = (lo + hi) >> 1; if (gid[mid] < g) lo = mid + 1; else hi = mid; }
  int s = lo;
  lo = s; hi = n;
  while (lo < hi) { int mid = (lo + hi) >> 1; if (gid[mid] < g + 1) lo = mid + 1; else hi = mid; }
  int e = lo;
  float acc = 0.f;
  if (s < e) {
    int cb = c >> 6, cc = c & 63;
    int b0 = s >> 6, b1 = (e - 1) >> 6;
    for (int b = b0; b <= b1; b++) {
      int sl = g - gid[b * 64];
      if ((unsigned)sl < 4u)
        acc += part[(((size_t)b * 4 + cb) * 4 + sl) * 64 + cc];
    }
  }
  out[g * 256 + c] = acc;
}

// ---------------- launch ----------------

extern "C" void kernel_launch(void* const* d_in, const int* in_sizes, int n_in,
                              void* d_out, int out_size, void* d_ws, size_t ws_size,
                              hipStream_t stream) {
  const float* x     = (const float*)d_in[0];
  const float* w     = (const float*)d_in[1];
  const float* W1    = (const float*)d_in[2];
  const float* Wfc   = (const float*)d_in[3];
  const float* gamma = (const float*)d_in[4];
  const float* beta  = (const float*)d_in[5];
  const float* W2    = (const float*)d_in[6];
  const float* W3    = (const float*)d_in[7];
  const int*   src   = (const int*)d_in[8];
  const int*   dst   = (const int*)d_in[9];
  const int*   gid   = (const int*)d_in[10];
  float* out = (float*)d_out;

  const int N = NN, E = NE;

  char* p = (char*)d_ws;
  auto alloc = [&](size_t bytes) {
    char* r = p;
    p += (bytes + 255) & ~(size_t)255;
    return r;
  };
  unsigned char* hout = (unsigned char*)alloc((size_t)NB_H * N);  // per-chunk out-hist (u8)
  unsigned char* hin  = (unsigned char*)alloc((size_t)NB_H * N);  // per-chunk in-hist -> binBase
  int*   din     = (int*)alloc((size_t)N * 4);
  float* onorm   = (float*)alloc((size_t)N * 4);
  float* inorm   = (float*)alloc((size_t)N * 4);
  int*   row_ptr = (int*)alloc((size_t)(N + 1) * 4);
  int*   bsum    = (int*)alloc(256 * 4);
  int*   rank    = (int*)alloc((size_t)E * 4);
  uint2* edge    = (uint2*)alloc((size_t)E * 8);  // interleaved {col, wse}
  float* part    = (float*)alloc((size_t)782 * 4 * 4 * 64 * 4);  // readout partials (3.2MB)
  unsigned short* xb    = (unsigned short*)alloc((size_t)N * 128 * 2);
  unsigned short* aggX  = (unsigned short*)alloc((size_t)N * 128 * 2);
  unsigned short* x1f1  = (unsigned short*)alloc((size_t)N * 512 * 2);
  unsigned short* y2    = (unsigned short*)alloc((size_t)N * 256 * 2);
  unsigned short* x2    = (unsigned short*)alloc((size_t)N * 256 * 2);
  unsigned short* aggx2 = (unsigned short*)alloc((size_t)N * 256 * 2);
  unsigned short* W1t   = (unsigned short*)alloc((size_t)256 * 128 * 2);
  unsigned short* Wfct  = (unsigned short*)alloc((size_t)256 * 128 * 2);
  unsigned short* W2t   = (unsigned short*)alloc((size_t)256 * 512 * 2);
  unsigned short* W3t   = (unsigned short*)alloc((size_t)256 * 256 * 2);

  const int nbS = (N + 255) / 256;  // 196

  prep_kernel<<<NB_H + XB + WTB, 1024, 0, stream>>>(src, dst, hout, hin, rank,
                                                    x, xb, W1, Wfc, W2, W3,
                                                    W1t, Wfct, W2t, W3t);
  norms_scan1<<<nbS, 256, 0, stream>>>(hout, hin, din, onorm, inorm, bsum, N);
  scan3_kernel<<<nbS, 256, 0, stream>>>(din, bsum, row_ptr, N, nbS);
  fill_kernel<<<(E + 255) / 256, 256, 0, stream>>>(src, dst, w, onorm, inorm, row_ptr,
                                                   rank, hin, edge, E);

  dim3 ggrid((N + 127) / 128, 2);  // 391 x 2

  // aggX' = agg(xb)
  spmm_bf16<0, 1><<<N, 64, 0, stream>>>(xb, 128, row_ptr, edge, aggX, 128);
  // z=0: x1 = relu(aggX@W1) -> x1f1[:,0:256] ; z=1: f1 = relu(LN(xb@Wfc)) -> x1f1[:,256:512]
  g12f_kernel<<<dim3(782, 1, 2), 256, 0, stream>>>(aggX, W1t, xb, Wfct, gamma, beta, x1f1, N);
  // y2 = x1f1 @ W2
  gemm_kernel<<<ggrid, 256, 0, stream>>>(x1f1, 512, W2t, 512, y2, 256, N, 0);
  // x2 = relu(agg'(y2))
  spmm_bf16<1, 2><<<N, 64, 0, stream>>>(y2, 256, row_ptr, edge, x2, 256);
  // aggx2 = agg'(x2)
  spmm_bf16<0, 2><<<N, 64, 0, stream>>>(x2, 256, row_ptr, edge, aggx2, 256);
  // x3 readout partials: fcln-style LDS-staged GEMM (x3 never materialized)
  gemm_ro3<<<dim3(782, 4), 256, 0, stream>>>(aggx2, W3t, gid, part, N);
  // deterministic cross-block reduce -> out
  readout_reduce<<<NG, 256, 0, stream>>>(part, gid, out, N);
}

// Round 14
// 416.381 us; speedup vs baseline: 1.0271x; 1.0271x over previous
//
#include <hip/hip_runtime.h>

#define NN 50000
#define NE 800000
#define NG 64
#define EPSF 1e-5f

typedef __bf16 bf16x8 __attribute__((ext_vector_type(8)));
typedef float f32x4 __attribute__((ext_vector_type(4)));

#define AS1 __attribute__((address_space(1)))
#define AS3 __attribute__((address_space(3)))

__device__ __forceinline__ void gl_lds16(const unsigned short* g, unsigned short* l) {
#if __has_builtin(__builtin_amdgcn_global_load_lds)
  __builtin_amdgcn_global_load_lds((const AS1 void*)g, (AS3 void*)l, 16, 0, 0);
#else
  *(uint4*)l = *(const uint4*)g;
#endif
}

__device__ __forceinline__ unsigned short f2bf(float f) {
  unsigned u = __builtin_bit_cast(unsigned, f);
  u += 0x7fff + ((u >> 16) & 1);  // RNE
  return (unsigned short)(u >> 16);
}
__device__ __forceinline__ float bf_lo(unsigned u) {
  return __builtin_bit_cast(float, u << 16);
}
__device__ __forceinline__ float bf_hi(unsigned u) {
  return __builtin_bit_cast(float, u & 0xffff0000u);
}

// ---------------- fused prep: u8 single-pass LDS hist | x->bf16 | weights->bf16^T --------
#define NB_H 64
#define EC   12500        // NE / NB_H
#define HWORDS 12500      // 50000 bins / 4 per word
#define XB   1563         // ceil(NN*128/4 / 1024)
#define XTOT 1600000      // NN*128/4
#define WTB  256          // 262144/1024
__global__ __launch_bounds__(1024) void prep_kernel(
    const int* __restrict__ src, const int* __restrict__ dst,
    unsigned char* __restrict__ hout, unsigned char* __restrict__ hin,
    int* __restrict__ rank,
    const float* __restrict__ x, unsigned short* __restrict__ xb,
    const float* __restrict__ W1, const float* __restrict__ Wfc,
    const float* __restrict__ W2, const float* __restrict__ W3,
    unsigned short* __restrict__ W1t, unsigned short* __restrict__ Wfct,
    unsigned short* __restrict__ W2t, unsigned short* __restrict__ W3t) {
  __shared__ unsigned hist[HWORDS];  // 50 KB
  int b = blockIdx.x;
  int tid = threadIdx.x;
  if (b < NB_H) {
    int e0 = b * EC;
#pragma unroll
    for (int ph = 0; ph < 2; ph++) {
      const int* key = ph ? src : dst;
      unsigned char* gh = (ph ? hout : hin) + (size_t)b * NN;
      for (int i = tid; i < HWORDS; i += 1024) hist[i] = 0u;
      __syncthreads();
      for (int i = tid; i < EC; i += 1024) {
        int k = key[e0 + i];
        int sh = (k & 3) << 3;
        unsigned old = atomicAdd(&hist[k >> 2], 1u << sh);
        if (ph == 0) rank[e0 + i] = (int)((old >> sh) & 0xffu);
      }
      __syncthreads();
      unsigned* gw = (unsigned*)gh;  // b*NN is 4-aligned (NN%4==0)
      for (int i = tid; i < HWORDS; i += 1024) gw[i] = hist[i];
      __syncthreads();
    }
  } else if (b < NB_H + XB) {
    int i = (b - NB_H) * 1024 + tid;
    if (i < XTOT) {
      float4 v = ((const float4*)x)[i];
      uint2 pk;
      pk.x = (unsigned)f2bf(v.x) | ((unsigned)f2bf(v.y) << 16);
      pk.y = (unsigned)f2bf(v.z) | ((unsigned)f2bf(v.w) << 16);
      ((uint2*)xb)[i] = pk;
    }
  } else {
    int i = (b - NB_H - XB) * 1024 + tid;  // 0..262143
    const float* W; unsigned short* Wt; int K, local;
    if (i < 32768)       { W = W1;  Wt = W1t;  K = 128; local = i; }
    else if (i < 65536)  { W = Wfc; Wt = Wfct; K = 128; local = i - 32768; }
    else if (i < 196608) { W = W2;  Wt = W2t;  K = 512; local = i - 65536; }
    else                 { W = W3;  Wt = W3t;  K = 256; local = i - 196608; }
    int n = local / K, k = local - n * K;
    Wt[local] = f2bf(W[(size_t)k * 256 + n]);
  }
}

// ---------------- norms + cross-block hist reduce/prefix + scan phase 1 ----------------
__global__ void norms_scan1(const unsigned char* __restrict__ hout,
                            unsigned char* __restrict__ hin,   // becomes binBase in place
                            int* __restrict__ din,
                            float* __restrict__ onorm, float* __restrict__ inorm,
                            int* __restrict__ bsum, int n) {
  int i = blockIdx.x * 256 + threadIdx.x;
  int d = 0;
  if (i < n) {
    int a = 0;
    for (int b = 0; b < NB_H; b++) a += hout[(size_t)b * NN + i];
    int run = 0;
    for (int b = 0; b < NB_H; b++) {  // in-place exclusive prefix over blocks
      int t = hin[(size_t)b * NN + i];
      hin[(size_t)b * NN + i] = (unsigned char)run;
      run += t;
    }
    d = run;
    din[i] = run;
    onorm[i] = rsqrtf((float)(a > 1 ? a : 1));
    inorm[i] = rsqrtf((float)(d > 1 ? d : 1));
  }
  int v = d;
#pragma unroll
  for (int off = 32; off > 0; off >>= 1) v += __shfl_down(v, off);
  __shared__ int ws[4];
  int wave = threadIdx.x >> 6, lane = threadIdx.x & 63;
  if (lane == 0) ws[wave] = v;
  __syncthreads();
  if (threadIdx.x == 0) bsum[blockIdx.x] = ws[0] + ws[1] + ws[2] + ws[3];
}

// ---------------- scan phase 2+3 fused: each block redundantly scans bsum ----------------
__global__ void scan3_kernel(const int* __restrict__ din, const int* __restrict__ bsum,
                             int* __restrict__ rp, int n, int nb) {
  int t = threadIdx.x;
  int lane = t & 63, wave = t >> 6;
  int bj = (t < nb) ? bsum[t] : 0;
  int pre = (t < (int)blockIdx.x) ? bj : 0;
  int p = pre, q = bj;
#pragma unroll
  for (int off = 32; off > 0; off >>= 1) {
    p += __shfl_down(p, off);
    q += __shfl_down(q, off);
  }
  __shared__ int red[8];
  __shared__ int baseS, totS;
  if (lane == 0) { red[wave] = p; red[4 + wave] = q; }
  __syncthreads();
  if (t == 0) {
    baseS = red[0] + red[1] + red[2] + red[3];
    totS  = red[4] + red[5] + red[6] + red[7];
  }
  __syncthreads();
  int i = blockIdx.x * 256 + t;
  int v = (i < n) ? din[i] : 0;
  __shared__ int tmp[256];
  tmp[t] = v;
  __syncthreads();
  for (int off = 1; off < 256; off <<= 1) {
    int x = (t >= off) ? tmp[t - off] : 0;
    __syncthreads();
    tmp[t] += x;
    __syncthreads();
  }
  if (i < n) rp[i] = tmp[t] - v + baseS;
  if (blockIdx.x == gridDim.x - 1 && t == 0) rp[n] = totS;
}

// ---------------- CSR fill, atomic-free; edge = {col, wse} interleaved ----------------
__global__ void fill_kernel(const int* __restrict__ src, const int* __restrict__ dst,
                            const float* __restrict__ w, const float* __restrict__ onorm,
                            const float* __restrict__ inorm,
                            const int* __restrict__ rp, const int* __restrict__ rank,
                            const unsigned char* __restrict__ binBase,
                            uint2* __restrict__ edge, int E) {
  int e = blockIdx.x * 256 + threadIdx.x;
  if (e < E) {
    int d = dst[e], s = src[e];
    int b = e / EC;  // histogram chunk that counted this edge
    int pos = rp[d] + (int)binBase[(size_t)b * NN + d] + rank[e];
    float wv = w[e] * onorm[s] * inorm[d];
    edge[pos] = make_uint2((unsigned)s, __builtin_bit_cast(unsigned, wv));
  }
}

// ---------------- SpMM (interleaved edges, 8-edge unroll) ----------------
template <int RELU, int NU>
__global__ __launch_bounds__(64) void spmm_bf16(
    const unsigned short* __restrict__ feat, int ldf,
    const int* __restrict__ rp, const uint2* __restrict__ edge,
    unsigned short* __restrict__ out, int ldo) {
  int v = blockIdx.x;
  int t = threadIdx.x;  // 64
  int beg = rp[v], end = rp[v + 1];
  float acc[2 * NU];
#pragma unroll
  for (int i = 0; i < 2 * NU; i++) acc[i] = 0.f;
  const unsigned short* base = feat + t * (2 * NU);
  int e = beg;
  for (; e + 8 <= end; e += 8) {
    int s[8]; float ww[8];
#pragma unroll
    for (int k = 0; k < 8; k++) {
      uint2 q = edge[e + k];
      s[k] = (int)q.x;
      ww[k] = __builtin_bit_cast(float, q.y);
    }
    unsigned u[8][NU];
#pragma unroll
    for (int k = 0; k < 8; k++) {
      const unsigned* pr = (const unsigned*)&base[(size_t)s[k] * ldf];
      if (NU == 2) { uint2 q = *(const uint2*)pr; u[k][0] = q.x; u[k][NU - 1] = q.y; }
      else u[k][0] = pr[0];
    }
#pragma unroll
    for (int k = 0; k < 8; k++)
#pragma unroll
      for (int j = 0; j < NU; j++) {
        acc[2 * j]     += ww[k] * bf_lo(u[k][j]);
        acc[2 * j + 1] += ww[k] * bf_hi(u[k][j]);
      }
  }
  for (; e < end; e++) {
    uint2 qe = edge[e];
    float w0 = __builtin_bit_cast(float, qe.y);
    const unsigned* pr = (const unsigned*)&base[(size_t)qe.x * ldf];
    unsigned u[NU];
    if (NU == 2) { uint2 q = *(const uint2*)pr; u[0] = q.x; u[NU - 1] = q.y; }
    else u[0] = pr[0];
#pragma unroll
    for (int j = 0; j < NU; j++) {
      acc[2 * j]     += w0 * bf_lo(u[j]);
      acc[2 * j + 1] += w0 * bf_hi(u[j]);
    }
  }
  unsigned o[NU];
#pragma unroll
  for (int j = 0; j < NU; j++) {
    float a = acc[2 * j], b = acc[2 * j + 1];
    if (RELU) { a = fmaxf(a, 0.f); b = fmaxf(b, 0.f); }
    o[j] = (unsigned)f2bf(a) | ((unsigned)f2bf(b) << 16);
  }
  unsigned* po = (unsigned*)&out[(size_t)v * ldo + t * (2 * NU)];
  if (NU == 2) *(uint2*)po = make_uint2(o[0], o[NU - 1]);
  else po[0] = o[0];
}

// ---------------- MFMA GEMM core: 128x128 tile, BK=64, double-buffered (R5-proven) ------
__device__ __forceinline__ void gemm_core(
    const unsigned short* __restrict__ A, int lda,
    const unsigned short* __restrict__ Bt, int K, int M,
    int bm, int bn, int relu,
    unsigned short (*As)[8192], unsigned short (*Bs)[8192],
    f32x4 (&acc)[4][4]) {
  const int tid = threadIdx.x;
  const int lane = tid & 63;
  const int m0 = bm * 128;
  const int n0 = bn * 128;

#pragma unroll
  for (int i = 0; i < 4; i++)
#pragma unroll
    for (int j = 0; j < 4; j++) acc[i][j] = (f32x4){0.f, 0.f, 0.f, 0.f};

  const unsigned short* pa[4];
  const unsigned short* pb[4];
#pragma unroll
  for (int i = 0; i < 4; i++) {
    int ch = i * 256 + tid;
    int sub = ch >> 6, sl = ch & 63;
    int mi = sub >> 1, kk = sub & 1;
    int row = mi * 16 + (sl & 15);
    int kc = kk * 32 + (sl >> 4) * 8;
    int gm = m0 + row; if (gm >= M) gm = M - 1;
    pa[i] = A + (size_t)gm * lda + kc;
    int gn = n0 + row;
    pb[i] = Bt + (size_t)gn * K + kc;
  }

  const int NT = K >> 6;
#pragma unroll
  for (int i = 0; i < 4; i++) {
    int ch8 = (i * 256 + tid) * 8;
    gl_lds16(pa[i], &As[0][ch8]);
    gl_lds16(pb[i], &Bs[0][ch8]);
  }
  __syncthreads();

  const int wv = tid >> 6;
  const int wm = wv >> 1, wn = wv & 1;
  int cur = 0;
  for (int t = 0; t < NT; t++) {
    if (t + 1 < NT) {
      int nk = (t + 1) << 6;
#pragma unroll
      for (int i = 0; i < 4; i++) {
        int ch8 = (i * 256 + tid) * 8;
        gl_lds16(pa[i] + nk, &As[cur ^ 1][ch8]);
        gl_lds16(pb[i] + nk, &Bs[cur ^ 1][ch8]);
      }
    }
#pragma unroll
    for (int kk = 0; kk < 2; kk++) {
      bf16x8 af[4], bfr[4];
#pragma unroll
      for (int i = 0; i < 4; i++)
        af[i] = *(const bf16x8*)&As[cur][((wm * 4 + i) * 2 + kk) * 512 + lane * 8];
#pragma unroll
      for (int j = 0; j < 4; j++)
        bfr[j] = *(const bf16x8*)&Bs[cur][((wn * 4 + j) * 2 + kk) * 512 + lane * 8];
#pragma unroll
      for (int i = 0; i < 4; i++)
#pragma unroll
        for (int j = 0; j < 4; j++)
          acc[i][j] = __builtin_amdgcn_mfma_f32_16x16x32_bf16(af[i], bfr[j], acc[i][j], 0, 0, 0);
    }
    __syncthreads();
    cur ^= 1;
  }
  if (relu) {
#pragma unroll
    for (int i = 0; i < 4; i++)
#pragma unroll
      for (int j = 0; j < 4; j++)
#pragma unroll
        for (int r = 0; r < 4; r++) acc[i][j][r] = fmaxf(acc[i][j][r], 0.f);
  }
}

__device__ __forceinline__ void gemm_store(
    const f32x4 (&acc)[4][4], unsigned short* __restrict__ C, int ldc,
    int col_off, int M, int bm, int bn) {
  const int tid = threadIdx.x;
  const int lane = tid & 63;
  const int wv = tid >> 6;
  const int wm = wv >> 1, wn = wv & 1;
  const int q = lane >> 4, r16 = lane & 15;
  const int m0 = bm * 128, n0 = bn * 128;
#pragma unroll
  for (int i = 0; i < 4; i++) {
    int rbase = m0 + wm * 64 + i * 16 + q * 4;
#pragma unroll
    for (int r = 0; r < 4; r++) {
      int gm = rbase + r;
      if (gm >= M) continue;
#pragma unroll
      for (int j = 0; j < 4; j++) {
        int gn = col_off + n0 + wn * 64 + j * 16 + r16;
        C[(size_t)gm * ldc + gn] = f2bf(acc[i][j][r]);
      }
    }
  }
}

// ---------------- fc GEMM (64x256, K=128 single tile) + LayerNorm + relu epilogue --------
__device__ __forceinline__ void fcln_body(
    const unsigned short* __restrict__ A, const unsigned short* __restrict__ Bt,
    const float* __restrict__ gamma, const float* __restrict__ beta,
    unsigned short* __restrict__ C, int M, unsigned short* lds) {
  const int tid = threadIdx.x;
  const int lane = tid & 63;
  const int w = tid >> 6;
  const int q = lane >> 4, r16 = lane & 15;
  const int m0 = blockIdx.x * 64;
  unsigned short* As = lds;          // 16 subtiles * 512 shorts (A 64x128)
  unsigned short* Bs = lds + 8192;   // 64 subtiles * 512 shorts (B^T 256x128)

#pragma unroll
  for (int i = 0; i < 4; i++) {
    int ch = i * 256 + tid;
    int st = ch >> 6, sl = ch & 63;
    int mi = st >> 2, kk = st & 3;
    int gm = m0 + mi * 16 + (sl & 15); if (gm >= M) gm = M - 1;
    int k = kk * 32 + (sl >> 4) * 8;
    gl_lds16(A + (size_t)gm * 128 + k, &As[ch * 8]);
  }
#pragma unroll
  for (int i = 0; i < 16; i++) {
    int ch = i * 256 + tid;
    int st = ch >> 6, sl = ch & 63;
    int ns = st >> 2, kk = st & 3;
    int n = ns * 16 + (sl & 15);
    int k = kk * 32 + (sl >> 4) * 8;
    gl_lds16(Bt + (size_t)n * 128 + k, &Bs[ch * 8]);
  }
  __syncthreads();

  f32x4 acc[4][4];
#pragma unroll
  for (int i = 0; i < 4; i++)
#pragma unroll
    for (int j = 0; j < 4; j++) acc[i][j] = (f32x4){0.f, 0.f, 0.f, 0.f};

#pragma unroll
  for (int kk = 0; kk < 4; kk++) {
    bf16x8 af[4], bfr[4];
#pragma unroll
    for (int i = 0; i < 4; i++)
      af[i] = *(const bf16x8*)&As[(i * 4 + kk) * 512 + lane * 8];
#pragma unroll
    for (int j = 0; j < 4; j++)
      bfr[j] = *(const bf16x8*)&Bs[((w * 4 + j) * 4 + kk) * 512 + lane * 8];
#pragma unroll
    for (int i = 0; i < 4; i++)
#pragma unroll
      for (int j = 0; j < 4; j++)
        acc[i][j] = __builtin_amdgcn_mfma_f32_16x16x32_bf16(af[i], bfr[j], acc[i][j], 0, 0, 0);
  }
  __syncthreads();  // LDS now reusable for reduction

  float* fws = (float*)lds;       // [4][64] wave partial sums
  float* fwq = fws + 256;         // [4][64] wave partial sumsq
  float* fmean = fwq + 256;       // [64]
  float* frs = fmean + 64;        // [64]

#pragma unroll
  for (int i = 0; i < 4; i++)
#pragma unroll
    for (int r = 0; r < 4; r++) {
      float s  = acc[i][0][r] + acc[i][1][r] + acc[i][2][r] + acc[i][3][r];
      float q2 = acc[i][0][r] * acc[i][0][r] + acc[i][1][r] * acc[i][1][r] +
                 acc[i][2][r] * acc[i][2][r] + acc[i][3][r] * acc[i][3][r];
#pragma unroll
      for (int off = 8; off > 0; off >>= 1) {
        s  += __shfl_down(s, off, 16);
        q2 += __shfl_down(q2, off, 16);
      }
      if (r16 == 0) {
        int row = i * 16 + q * 4 + r;
        fws[w * 64 + row] = s;
        fwq[w * 64 + row] = q2;
      }
    }
  __syncthreads();
  if (tid < 64) {
    float S = fws[tid] + fws[64 + tid] + fws[128 + tid] + fws[192 + tid];
    float Q = fwq[tid] + fwq[64 + tid] + fwq[128 + tid] + fwq[192 + tid];
    float mean = S * (1.f / 256.f);
    float var = Q * (1.f / 256.f) - mean * mean;
    fmean[tid] = mean;
    frs[tid] = rsqrtf(var + EPSF);
  }
  __syncthreads();

  float g4[4], b4[4];
#pragma unroll
  for (int j = 0; j < 4; j++) {
    int c = w * 64 + j * 16 + r16;
    g4[j] = gamma[c];
    b4[j] = beta[c];
  }
#pragma unroll
  for (int i = 0; i < 4; i++)
#pragma unroll
    for (int r = 0; r < 4; r++) {
      int row = i * 16 + q * 4 + r;
      int gm = m0 + row;
      if (gm >= M) continue;
      float mean = fmean[row], rs = frs[row];
#pragma unroll
      for (int j = 0; j < 4; j++) {
        int c = w * 64 + j * 16 + r16;
        float y = (acc[i][j][r] - mean) * rs * g4[j] + b4[j];
        C[(size_t)gm * 512 + 256 + c] = f2bf(fmaxf(y, 0.f));
      }
    }
}

// z=0: x1 = relu(aggX@W1) -> x1f1[:,0:256] (128x128 tiles, bm=bx>>1, bn=bx&1)
// z=1: f1 = relu(LN(xb@Wfc)) -> x1f1[:,256:512] (64x256 tiles, m0=bx*64)
__global__ __launch_bounds__(256) void g12f_kernel(
    const unsigned short* __restrict__ A0, const unsigned short* __restrict__ B0,
    const unsigned short* __restrict__ A1, const unsigned short* __restrict__ B1,
    const float* __restrict__ gamma, const float* __restrict__ beta,
    unsigned short* __restrict__ C, int M) {
  __shared__ unsigned short lds[40960];  // 80 KB
  if (blockIdx.z == 0) {
    f32x4 acc[4][4];
    int bm = blockIdx.x >> 1, bn = blockIdx.x & 1;
    gemm_core(A0, 128, B0, 128, M, bm, bn, 1,
              (unsigned short (*)[8192])lds,
              (unsigned short (*)[8192])(lds + 16384), acc);
    gemm_store(acc, C, 512, 0, M, bm, bn);
  } else {
    fcln_body(A1, B1, gamma, beta, C, M, lds);
  }
}

// generic GEMM (y2 = x1f1 @ W2 ; x3 = relu(aggx2 @ W3))
__global__ __launch_bounds__(256) void gemm_kernel(
    const unsigned short* __restrict__ A, int lda,
    const unsigned short* __restrict__ Bt, int K,
    unsigned short* __restrict__ C, int ldc, int M, int relu) {
  __shared__ unsigned short As[2][8192];
  __shared__ unsigned short Bs[2][8192];
  f32x4 acc[4][4];
  gemm_core(A, lda, Bt, K, M, blockIdx.x, blockIdx.y, relu, As, Bs, acc);
  gemm_store(acc, C, ldc, 0, M, blockIdx.x, blockIdx.y);
}

// ---------------- per-graph readout (graph_ids sorted), x3 bf16 -> fp32 sums ------------
// R5-proven form: never appeared in top-5 (<15us). One graph per block.x, 8 parts.
__global__ void readout_kernel(const unsigned short* __restrict__ x3,
                               const int* __restrict__ gid,
                               float* __restrict__ out, int n) {
  int g = blockIdx.x;
  int part = blockIdx.y;  // 8 parts
  int f = threadIdx.x;    // 256
  int lo = 0, hi = n;
  while (lo < hi) { int mid = (lo + hi) >> 1; if (gid[mid] < g) lo = mid + 1; else hi = mid; }
  int s = lo;
  lo = s; hi = n;
  while (lo < hi) { int mid = (lo + hi) >> 1; if (gid[mid] < g + 1) lo = mid + 1; else hi = mid; }
  int e = lo;
  int len = e - s;
  if (len <= 0) return;
  int chunk = (len + 7) / 8;
  int cs = s + part * chunk;
  int ce = cs + chunk; if (ce > e) ce = e;
  if (cs >= ce) return;
  float acc = 0.f;
  for (int v = cs; v < ce; v++) acc += bf_lo((unsigned)x3[(size_t)v * 256 + f]);
  atomicAdd(&out[g * 256 + f], acc);
}

// ---------------- launch ----------------

extern "C" void kernel_launch(void* const* d_in, const int* in_sizes, int n_in,
                              void* d_out, int out_size, void* d_ws, size_t ws_size,
                              hipStream_t stream) {
  const float* x     = (const float*)d_in[0];
  const float* w     = (const float*)d_in[1];
  const float* W1    = (const float*)d_in[2];
  const float* Wfc   = (const float*)d_in[3];
  const float* gamma = (const float*)d_in[4];
  const float* beta  = (const float*)d_in[5];
  const float* W2    = (const float*)d_in[6];
  const float* W3    = (const float*)d_in[7];
  const int*   src   = (const int*)d_in[8];
  const int*   dst   = (const int*)d_in[9];
  const int*   gid   = (const int*)d_in[10];
  float* out = (float*)d_out;

  const int N = NN, E = NE;

  char* p = (char*)d_ws;
  auto alloc = [&](size_t bytes) {
    char* r = p;
    p += (bytes + 255) & ~(size_t)255;
    return r;
  };
  unsigned char* hout = (unsigned char*)alloc((size_t)NB_H * N);  // per-chunk out-hist (u8)
  unsigned char* hin  = (unsigned char*)alloc((size_t)NB_H * N);  // per-chunk in-hist -> binBase
  int*   din     = (int*)alloc((size_t)N * 4);
  float* onorm   = (float*)alloc((size_t)N * 4);
  float* inorm   = (float*)alloc((size_t)N * 4);
  int*   row_ptr = (int*)alloc((size_t)(N + 1) * 4);
  int*   bsum    = (int*)alloc(256 * 4);
  int*   rank    = (int*)alloc((size_t)E * 4);
  uint2* edge    = (uint2*)alloc((size_t)E * 8);  // interleaved {col, wse}
  unsigned short* xb    = (unsigned short*)alloc((size_t)N * 128 * 2);
  unsigned short* aggX  = (unsigned short*)alloc((size_t)N * 128 * 2);
  unsigned short* x1f1  = (unsigned short*)alloc((size_t)N * 512 * 2);
  unsigned short* y2    = (unsigned short*)alloc((size_t)N * 256 * 2);
  unsigned short* x2    = (unsigned short*)alloc((size_t)N * 256 * 2);
  unsigned short* aggx2 = (unsigned short*)alloc((size_t)N * 256 * 2);
  unsigned short* W1t   = (unsigned short*)alloc((size_t)256 * 128 * 2);
  unsigned short* Wfct  = (unsigned short*)alloc((size_t)256 * 128 * 2);
  unsigned short* W2t   = (unsigned short*)alloc((size_t)256 * 512 * 2);
  unsigned short* W3t   = (unsigned short*)alloc((size_t)256 * 256 * 2);
  unsigned short* x3 = x1f1;  // x1f1 dead after y2 GEMM; reuse storage

  hipMemsetAsync(out, 0, (size_t)NG * 256 * 4, stream);

  const int nbS = (N + 255) / 256;  // 196

  prep_kernel<<<NB_H + XB + WTB, 1024, 0, stream>>>(src, dst, hout, hin, rank,
                                                    x, xb, W1, Wfc, W2, W3,
                                                    W1t, Wfct, W2t, W3t);
  norms_scan1<<<nbS, 256, 0, stream>>>(hout, hin, din, onorm, inorm, bsum, N);
  scan3_kernel<<<nbS, 256, 0, stream>>>(din, bsum, row_ptr, N, nbS);
  fill_kernel<<<(E + 255) / 256, 256, 0, stream>>>(src, dst, w, onorm, inorm, row_ptr,
                                                   rank, hin, edge, E);

  dim3 ggrid((N + 127) / 128, 2);  // 391 x 2

  // aggX' = agg(xb)
  spmm_bf16<0, 1><<<N, 64, 0, stream>>>(xb, 128, row_ptr, edge, aggX, 128);
  // z=0: x1 = relu(aggX@W1) -> x1f1[:,0:256] ; z=1: f1 = relu(LN(xb@Wfc)) -> x1f1[:,256:512]
  g12f_kernel<<<dim3(782, 1, 2), 256, 0, stream>>>(aggX, W1t, xb, Wfct, gamma, beta, x1f1, N);
  // y2 = x1f1 @ W2
  gemm_kernel<<<ggrid, 256, 0, stream>>>(x1f1, 512, W2t, 512, y2, 256, N, 0);
  // x2 = relu(agg'(y2))
  spmm_bf16<1, 2><<<N, 64, 0, stream>>>(y2, 256, row_ptr, edge, x2, 256);
  // aggx2 = agg'(x2)
  spmm_bf16<0, 2><<<N, 64, 0, stream>>>(x2, 256, row_ptr, edge, aggx2, 256);
  // x3 = relu(aggx2 @ W3) (R5-proven split: plain gemm, <57us, never topped profile)
  gemm_kernel<<<ggrid, 256, 0, stream>>>(aggx2, 256, W3t, 256, x3, 256, N, 1);
  // readout (R5-proven split)
  readout_kernel<<<dim3(NG, 8), 256, 0, stream>>>(x3, gid, out, N);
}

// Round 16
// 405.772 us; speedup vs baseline: 1.0540x; 1.0261x over previous
//
#include <hip/hip_runtime.h>

#define NN 50000
#define NE 800000
#define NG 64
#define EPSF 1e-5f

typedef __bf16 bf16x8 __attribute__((ext_vector_type(8)));
typedef float f32x4 __attribute__((ext_vector_type(4)));

#define AS1 __attribute__((address_space(1)))
#define AS3 __attribute__((address_space(3)))

__device__ __forceinline__ void gl_lds16(const unsigned short* g, unsigned short* l) {
#if __has_builtin(__builtin_amdgcn_global_load_lds)
  __builtin_amdgcn_global_load_lds((const AS1 void*)g, (AS3 void*)l, 16, 0, 0);
#else
  *(uint4*)l = *(const uint4*)g;
#endif
}

__device__ __forceinline__ unsigned short f2bf(float f) {
  unsigned u = __builtin_bit_cast(unsigned, f);
  u += 0x7fff + ((u >> 16) & 1);  // RNE
  return (unsigned short)(u >> 16);
}
__device__ __forceinline__ float bf_lo(unsigned u) {
  return __builtin_bit_cast(float, u << 16);
}
__device__ __forceinline__ float bf_hi(unsigned u) {
  return __builtin_bit_cast(float, u & 0xffff0000u);
}

// ---------------- fused prep: u8 single-pass LDS hist | x->bf16 | weights->bf16^T --------
#define NB_H 64
#define EC   12500        // NE / NB_H
#define HWORDS 12500      // 50000 bins / 4 per word
#define XB   1563         // ceil(NN*128/4 / 1024)
#define XTOT 1600000      // NN*128/4
#define WTB  256          // 262144/1024
__global__ __launch_bounds__(1024) void prep_kernel(
    const int* __restrict__ src, const int* __restrict__ dst,
    unsigned char* __restrict__ hout, unsigned char* __restrict__ hin,
    int* __restrict__ rank,
    const float* __restrict__ x, unsigned short* __restrict__ xb,
    const float* __restrict__ W1, const float* __restrict__ Wfc,
    const float* __restrict__ W2, const float* __restrict__ W3,
    unsigned short* __restrict__ W1t, unsigned short* __restrict__ Wfct,
    unsigned short* __restrict__ W2t, unsigned short* __restrict__ W3t) {
  __shared__ unsigned hist[HWORDS];  // 50 KB
  int b = blockIdx.x;
  int tid = threadIdx.x;
  if (b < NB_H) {
    int e0 = b * EC;
#pragma unroll
    for (int ph = 0; ph < 2; ph++) {
      const int* key = ph ? src : dst;
      unsigned char* gh = (ph ? hout : hin) + (size_t)b * NN;
      for (int i = tid; i < HWORDS; i += 1024) hist[i] = 0u;
      __syncthreads();
      for (int i = tid; i < EC; i += 1024) {
        int k = key[e0 + i];
        int sh = (k & 3) << 3;
        unsigned old = atomicAdd(&hist[k >> 2], 1u << sh);
        if (ph == 0) rank[e0 + i] = (int)((old >> sh) & 0xffu);
      }
      __syncthreads();
      unsigned* gw = (unsigned*)gh;  // b*NN is 4-aligned (NN%4==0)
      for (int i = tid; i < HWORDS; i += 1024) gw[i] = hist[i];
      __syncthreads();
    }
  } else if (b < NB_H + XB) {
    int i = (b - NB_H) * 1024 + tid;
    if (i < XTOT) {
      float4 v = ((const float4*)x)[i];
      uint2 pk;
      pk.x = (unsigned)f2bf(v.x) | ((unsigned)f2bf(v.y) << 16);
      pk.y = (unsigned)f2bf(v.z) | ((unsigned)f2bf(v.w) << 16);
      ((uint2*)xb)[i] = pk;
    }
  } else {
    int i = (b - NB_H - XB) * 1024 + tid;  // 0..262143
    const float* W; unsigned short* Wt; int K, local;
    if (i < 32768)       { W = W1;  Wt = W1t;  K = 128; local = i; }
    else if (i < 65536)  { W = Wfc; Wt = Wfct; K = 128; local = i - 32768; }
    else if (i < 196608) { W = W2;  Wt = W2t;  K = 512; local = i - 65536; }
    else                 { W = W3;  Wt = W3t;  K = 256; local = i - 196608; }
    int n = local / K, k = local - n * K;
    Wt[local] = f2bf(W[(size_t)k * 256 + n]);
  }
}

// ---------------- norms + cross-block hist reduce/prefix + scan phase 1 ----------------
__global__ void norms_scan1(const unsigned char* __restrict__ hout,
                            unsigned char* __restrict__ hin,   // becomes binBase in place
                            int* __restrict__ din,
                            float* __restrict__ onorm, float* __restrict__ inorm,
                            int* __restrict__ bsum, int n) {
  int i = blockIdx.x * 256 + threadIdx.x;
  int d = 0;
  if (i < n) {
    int a = 0;
    for (int b = 0; b < NB_H; b++) a += hout[(size_t)b * NN + i];
    int run = 0;
    for (int b = 0; b < NB_H; b++) {  // in-place exclusive prefix over blocks
      int t = hin[(size_t)b * NN + i];
      hin[(size_t)b * NN + i] = (unsigned char)run;
      run += t;
    }
    d = run;
    din[i] = run;
    onorm[i] = rsqrtf((float)(a > 1 ? a : 1));
    inorm[i] = rsqrtf((float)(d > 1 ? d : 1));
  }
  int v = d;
#pragma unroll
  for (int off = 32; off > 0; off >>= 1) v += __shfl_down(v, off);
  __shared__ int ws[4];
  int wave = threadIdx.x >> 6, lane = threadIdx.x & 63;
  if (lane == 0) ws[wave] = v;
  __syncthreads();
  if (threadIdx.x == 0) bsum[blockIdx.x] = ws[0] + ws[1] + ws[2] + ws[3];
}

// ---------------- scan phase 2+3 fused: each block redundantly scans bsum ----------------
__global__ void scan3_kernel(const int* __restrict__ din, const int* __restrict__ bsum,
                             int* __restrict__ rp, int n, int nb) {
  int t = threadIdx.x;
  int lane = t & 63, wave = t >> 6;
  int bj = (t < nb) ? bsum[t] : 0;
  int pre = (t < (int)blockIdx.x) ? bj : 0;
  int p = pre, q = bj;
#pragma unroll
  for (int off = 32; off > 0; off >>= 1) {
    p += __shfl_down(p, off);
    q += __shfl_down(q, off);
  }
  __shared__ int red[8];
  __shared__ int baseS, totS;
  if (lane == 0) { red[wave] = p; red[4 + wave] = q; }
  __syncthreads();
  if (t == 0) {
    baseS = red[0] + red[1] + red[2] + red[3];
    totS  = red[4] + red[5] + red[6] + red[7];
  }
  __syncthreads();
  int i = blockIdx.x * 256 + t;
  int v = (i < n) ? din[i] : 0;
  __shared__ int tmp[256];
  tmp[t] = v;
  __syncthreads();
  for (int off = 1; off < 256; off <<= 1) {
    int x = (t >= off) ? tmp[t - off] : 0;
    __syncthreads();
    tmp[t] += x;
    __syncthreads();
  }
  if (i < n) rp[i] = tmp[t] - v + baseS;
  if (blockIdx.x == gridDim.x - 1 && t == 0) rp[n] = totS;
}

// ---------------- CSR fill, atomic-free; edge = {col, wse} interleaved ----------------
__global__ void fill_kernel(const int* __restrict__ src, const int* __restrict__ dst,
                            const float* __restrict__ w, const float* __restrict__ onorm,
                            const float* __restrict__ inorm,
                            const int* __restrict__ rp, const int* __restrict__ rank,
                            const unsigned char* __restrict__ binBase,
                            uint2* __restrict__ edge, int E) {
  int e = blockIdx.x * 256 + threadIdx.x;
  if (e < E) {
    int d = dst[e], s = src[e];
    int b = e / EC;  // histogram chunk that counted this edge
    int pos = rp[d] + (int)binBase[(size_t)b * NN + d] + rank[e];
    float wv = w[e] * onorm[s] * inorm[d];
    edge[pos] = make_uint2((unsigned)s, __builtin_bit_cast(unsigned, wv));
  }
}

// ---------------- SpMM: 16-edge unroll, MLP-forcing launch bounds ----------------------
// R14 postmortem: VGPR_Count=24 < the 8-edge live set (32 regs) -> compiler serialized
// the gather chain (same starvation signature as R11's gemm_ro2). Widen to 16 edges and
// raise the VGPR budget via __launch_bounds__(64,4) (16 waves/CU cap, 128 VGPR) to force
// real load concurrency. Decisive test of MLP-limit vs fabric-floor for the 3.7 TB/s.
template <int RELU, int NU>
__global__ __launch_bounds__(64, 4) void spmm_bf16(
    const unsigned short* __restrict__ feat, int ldf,
    const int* __restrict__ rp, const uint2* __restrict__ edge,
    unsigned short* __restrict__ out, int ldo) {
  int v = blockIdx.x;
  int t = threadIdx.x;  // 64
  int beg = rp[v], end = rp[v + 1];
  float acc[2 * NU];
#pragma unroll
  for (int i = 0; i < 2 * NU; i++) acc[i] = 0.f;
  const unsigned short* base = feat + t * (2 * NU);
  int e = beg;
  for (; e + 16 <= end; e += 16) {
    int s[16]; float ww[16];
#pragma unroll
    for (int k = 0; k < 16; k++) {
      uint2 q = edge[e + k];
      s[k] = (int)q.x;
      ww[k] = __builtin_bit_cast(float, q.y);
    }
    unsigned u[16][NU];
#pragma unroll
    for (int k = 0; k < 16; k++) {
      const unsigned* pr = (const unsigned*)&base[(size_t)s[k] * ldf];
      if (NU == 2) { uint2 q = *(const uint2*)pr; u[k][0] = q.x; u[k][NU - 1] = q.y; }
      else u[k][0] = pr[0];
    }
#pragma unroll
    for (int k = 0; k < 16; k++)
#pragma unroll
      for (int j = 0; j < NU; j++) {
        acc[2 * j]     += ww[k] * bf_lo(u[k][j]);
        acc[2 * j + 1] += ww[k] * bf_hi(u[k][j]);
      }
  }
  for (; e + 8 <= end; e += 8) {
    int s[8]; float ww[8];
#pragma unroll
    for (int k = 0; k < 8; k++) {
      uint2 q = edge[e + k];
      s[k] = (int)q.x;
      ww[k] = __builtin_bit_cast(float, q.y);
    }
    unsigned u[8][NU];
#pragma unroll
    for (int k = 0; k < 8; k++) {
      const unsigned* pr = (const unsigned*)&base[(size_t)s[k] * ldf];
      if (NU == 2) { uint2 q = *(const uint2*)pr; u[k][0] = q.x; u[k][NU - 1] = q.y; }
      else u[k][0] = pr[0];
    }
#pragma unroll
    for (int k = 0; k < 8; k++)
#pragma unroll
      for (int j = 0; j < NU; j++) {
        acc[2 * j]     += ww[k] * bf_lo(u[k][j]);
        acc[2 * j + 1] += ww[k] * bf_hi(u[k][j]);
      }
  }
  for (; e < end; e++) {
    uint2 qe = edge[e];
    float w0 = __builtin_bit_cast(float, qe.y);
    const unsigned* pr = (const unsigned*)&base[(size_t)qe.x * ldf];
    unsigned u[NU];
    if (NU == 2) { uint2 q = *(const uint2*)pr; u[0] = q.x; u[NU - 1] = q.y; }
    else u[0] = pr[0];
#pragma unroll
    for (int j = 0; j < NU; j++) {
      acc[2 * j]     += w0 * bf_lo(u[j]);
      acc[2 * j + 1] += w0 * bf_hi(u[j]);
    }
  }
  unsigned o[NU];
#pragma unroll
  for (int j = 0; j < NU; j++) {
    float a = acc[2 * j], b = acc[2 * j + 1];
    if (RELU) { a = fmaxf(a, 0.f); b = fmaxf(b, 0.f); }
    o[j] = (unsigned)f2bf(a) | ((unsigned)f2bf(b) << 16);
  }
  unsigned* po = (unsigned*)&out[(size_t)v * ldo + t * (2 * NU)];
  if (NU == 2) *(uint2*)po = make_uint2(o[0], o[NU - 1]);
  else po[0] = o[0];
}

// ---------------- MFMA GEMM core: 128x128 tile, BK=64, double-buffered (R5-proven) ------
__device__ __forceinline__ void gemm_core(
    const unsigned short* __restrict__ A, int lda,
    const unsigned short* __restrict__ Bt, int K, int M,
    int bm, int bn, int relu,
    unsigned short (*As)[8192], unsigned short (*Bs)[8192],
    f32x4 (&acc)[4][4]) {
  const int tid = threadIdx.x;
  const int lane = tid & 63;
  const int m0 = bm * 128;
  const int n0 = bn * 128;

#pragma unroll
  for (int i = 0; i < 4; i++)
#pragma unroll
    for (int j = 0; j < 4; j++) acc[i][j] = (f32x4){0.f, 0.f, 0.f, 0.f};

  const unsigned short* pa[4];
  const unsigned short* pb[4];
#pragma unroll
  for (int i = 0; i < 4; i++) {
    int ch = i * 256 + tid;
    int sub = ch >> 6, sl = ch & 63;
    int mi = sub >> 1, kk = sub & 1;
    int row = mi * 16 + (sl & 15);
    int kc = kk * 32 + (sl >> 4) * 8;
    int gm = m0 + row; if (gm >= M) gm = M - 1;
    pa[i] = A + (size_t)gm * lda + kc;
    int gn = n0 + row;
    pb[i] = Bt + (size_t)gn * K + kc;
  }

  const int NT = K >> 6;
#pragma unroll
  for (int i = 0; i < 4; i++) {
    int ch8 = (i * 256 + tid) * 8;
    gl_lds16(pa[i], &As[0][ch8]);
    gl_lds16(pb[i], &Bs[0][ch8]);
  }
  __syncthreads();

  const int wv = tid >> 6;
  const int wm = wv >> 1, wn = wv & 1;
  int cur = 0;
  for (int t = 0; t < NT; t++) {
    if (t + 1 < NT) {
      int nk = (t + 1) << 6;
#pragma unroll
      for (int i = 0; i < 4; i++) {
        int ch8 = (i * 256 + tid) * 8;
        gl_lds16(pa[i] + nk, &As[cur ^ 1][ch8]);
        gl_lds16(pb[i] + nk, &Bs[cur ^ 1][ch8]);
      }
    }
#pragma unroll
    for (int kk = 0; kk < 2; kk++) {
      bf16x8 af[4], bfr[4];
#pragma unroll
      for (int i = 0; i < 4; i++)
        af[i] = *(const bf16x8*)&As[cur][((wm * 4 + i) * 2 + kk) * 512 + lane * 8];
#pragma unroll
      for (int j = 0; j < 4; j++)
        bfr[j] = *(const bf16x8*)&Bs[cur][((wn * 4 + j) * 2 + kk) * 512 + lane * 8];
#pragma unroll
      for (int i = 0; i < 4; i++)
#pragma unroll
        for (int j = 0; j < 4; j++)
          acc[i][j] = __builtin_amdgcn_mfma_f32_16x16x32_bf16(af[i], bfr[j], acc[i][j], 0, 0, 0);
    }
    __syncthreads();
    cur ^= 1;
  }
  if (relu) {
#pragma unroll
    for (int i = 0; i < 4; i++)
#pragma unroll
      for (int j = 0; j < 4; j++)
#pragma unroll
        for (int r = 0; r < 4; r++) acc[i][j][r] = fmaxf(acc[i][j][r], 0.f);
  }
}

__device__ __forceinline__ void gemm_store(
    const f32x4 (&acc)[4][4], unsigned short* __restrict__ C, int ldc,
    int col_off, int M, int bm, int bn) {
  const int tid = threadIdx.x;
  const int lane = tid & 63;
  const int wv = tid >> 6;
  const int wm = wv >> 1, wn = wv & 1;
  const int q = lane >> 4, r16 = lane & 15;
  const int m0 = bm * 128, n0 = bn * 128;
#pragma unroll
  for (int i = 0; i < 4; i++) {
    int rbase = m0 + wm * 64 + i * 16 + q * 4;
#pragma unroll
    for (int r = 0; r < 4; r++) {
      int gm = rbase + r;
      if (gm >= M) continue;
#pragma unroll
      for (int j = 0; j < 4; j++) {
        int gn = col_off + n0 + wn * 64 + j * 16 + r16;
        C[(size_t)gm * ldc + gn] = f2bf(acc[i][j][r]);
      }
    }
  }
}

// ---------------- fc GEMM (64x256, K=128 single tile) + LayerNorm + relu epilogue --------
__device__ __forceinline__ void fcln_body(
    const unsigned short* __restrict__ A, const unsigned short* __restrict__ Bt,
    const float* __restrict__ gamma, const float* __restrict__ beta,
    unsigned short* __restrict__ C, int M, unsigned short* lds) {
  const int tid = threadIdx.x;
  const int lane = tid & 63;
  const int w = tid >> 6;
  const int q = lane >> 4, r16 = lane & 15;
  const int m0 = blockIdx.x * 64;
  unsigned short* As = lds;          // 16 subtiles * 512 shorts (A 64x128)
  unsigned short* Bs = lds + 8192;   // 64 subtiles * 512 shorts (B^T 256x128)

#pragma unroll
  for (int i = 0; i < 4; i++) {
    int ch = i * 256 + tid;
    int st = ch >> 6, sl = ch & 63;
    int mi = st >> 2, kk = st & 3;
    int gm = m0 + mi * 16 + (sl & 15); if (gm >= M) gm = M - 1;
    int k = kk * 32 + (sl >> 4) * 8;
    gl_lds16(A + (size_t)gm * 128 + k, &As[ch * 8]);
  }
#pragma unroll
  for (int i = 0; i < 16; i++) {
    int ch = i * 256 + tid;
    int st = ch >> 6, sl = ch & 63;
    int ns = st >> 2, kk = st & 3;
    int n = ns * 16 + (sl & 15);
    int k = kk * 32 + (sl >> 4) * 8;
    gl_lds16(Bt + (size_t)n * 128 + k, &Bs[ch * 8]);
  }
  __syncthreads();

  f32x4 acc[4][4];
#pragma unroll
  for (int i = 0; i < 4; i++)
#pragma unroll
    for (int j = 0; j < 4; j++) acc[i][j] = (f32x4){0.f, 0.f, 0.f, 0.f};

#pragma unroll
  for (int kk = 0; kk < 4; kk++) {
    bf16x8 af[4], bfr[4];
#pragma unroll
    for (int i = 0; i < 4; i++)
      af[i] = *(const bf16x8*)&As[(i * 4 + kk) * 512 + lane * 8];
#pragma unroll
    for (int j = 0; j < 4; j++)
      bfr[j] = *(const bf16x8*)&Bs[((w * 4 + j) * 4 + kk) * 512 + lane * 8];
#pragma unroll
    for (int i = 0; i < 4; i++)
#pragma unroll
      for (int j = 0; j < 4; j++)
        acc[i][j] = __builtin_amdgcn_mfma_f32_16x16x32_bf16(af[i], bfr[j], acc[i][j], 0, 0, 0);
  }
  __syncthreads();  // LDS now reusable for reduction

  float* fws = (float*)lds;       // [4][64] wave partial sums
  float* fwq = fws + 256;         // [4][64] wave partial sumsq
  float* fmean = fwq + 256;       // [64]
  float* frs = fmean + 64;        // [64]

#pragma unroll
  for (int i = 0; i < 4; i++)
#pragma unroll
    for (int r = 0; r < 4; r++) {
      float s  = acc[i][0][r] + acc[i][1][r] + acc[i][2][r] + acc[i][3][r];
      float q2 = acc[i][0][r] * acc[i][0][r] + acc[i][1][r] * acc[i][1][r] +
                 acc[i][2][r] * acc[i][2][r] + acc[i][3][r] * acc[i][3][r];
#pragma unroll
      for (int off = 8; off > 0; off >>= 1) {
        s  += __shfl_down(s, off, 16);
        q2 += __shfl_down(q2, off, 16);
      }
      if (r16 == 0) {
        int row = i * 16 + q * 4 + r;
        fws[w * 64 + row] = s;
        fwq[w * 64 + row] = q2;
      }
    }
  __syncthreads();
  if (tid < 64) {
    float S = fws[tid] + fws[64 + tid] + fws[128 + tid] + fws[192 + tid];
    float Q = fwq[tid] + fwq[64 + tid] + fwq[128 + tid] + fwq[192 + tid];
    float mean = S * (1.f / 256.f);
    float var = Q * (1.f / 256.f) - mean * mean;
    fmean[tid] = mean;
    frs[tid] = rsqrtf(var + EPSF);
  }
  __syncthreads();

  float g4[4], b4[4];
#pragma unroll
  for (int j = 0; j < 4; j++) {
    int c = w * 64 + j * 16 + r16;
    g4[j] = gamma[c];
    b4[j] = beta[c];
  }
#pragma unroll
  for (int i = 0; i < 4; i++)
#pragma unroll
    for (int r = 0; r < 4; r++) {
      int row = i * 16 + q * 4 + r;
      int gm = m0 + row;
      if (gm >= M) continue;
      float mean = fmean[row], rs = frs[row];
#pragma unroll
      for (int j = 0; j < 4; j++) {
        int c = w * 64 + j * 16 + r16;
        float y = (acc[i][j][r] - mean) * rs * g4[j] + b4[j];
        C[(size_t)gm * 512 + 256 + c] = f2bf(fmaxf(y, 0.f));
      }
    }
}

// z=0: x1 = relu(aggX@W1) -> x1f1[:,0:256] (128x128 tiles, bm=bx>>1, bn=bx&1)
// z=1: f1 = relu(LN(xb@Wfc)) -> x1f1[:,256:512] (64x256 tiles, m0=bx*64)
__global__ __launch_bounds__(256) void g12f_kernel(
    const unsigned short* __restrict__ A0, const unsigned short* __restrict__ B0,
    const unsigned short* __restrict__ A1, const unsigned short* __restrict__ B1,
    const float* __restrict__ gamma, const float* __restrict__ beta,
    unsigned short* __restrict__ C, int M) {
  __shared__ unsigned short lds[40960];  // 80 KB
  if (blockIdx.z == 0) {
    f32x4 acc[4][4];
    int bm = blockIdx.x >> 1, bn = blockIdx.x & 1;
    gemm_core(A0, 128, B0, 128, M, bm, bn, 1,
              (unsigned short (*)[8192])lds,
              (unsigned short (*)[8192])(lds + 16384), acc);
    gemm_store(acc, C, 512, 0, M, bm, bn);
  } else {
    fcln_body(A1, B1, gamma, beta, C, M, lds);
  }
}

// generic GEMM (y2 = x1f1 @ W2 ; x3 = relu(aggx2 @ W3))
__global__ __launch_bounds__(256) void gemm_kernel(
    const unsigned short* __restrict__ A, int lda,
    const unsigned short* __restrict__ Bt, int K,
    unsigned short* __restrict__ C, int ldc, int M, int relu) {
  __shared__ unsigned short As[2][8192];
  __shared__ unsigned short Bs[2][8192];
  f32x4 acc[4][4];
  gemm_core(A, lda, Bt, K, M, blockIdx.x, blockIdx.y, relu, As, Bs, acc);
  gemm_store(acc, C, ldc, 0, M, blockIdx.x, blockIdx.y);
}

// ---------------- per-graph readout (graph_ids sorted), x3 bf16 -> fp32 sums ------------
__global__ void readout_kernel(const unsigned short* __restrict__ x3,
                               const int* __restrict__ gid,
                               float* __restrict__ out, int n) {
  int g = blockIdx.x;
  int part = blockIdx.y;  // 8 parts
  int f = threadIdx.x;    // 256
  int lo = 0, hi = n;
  while (lo < hi) { int mid = (lo + hi) >> 1; if (gid[mid] < g) lo = mid + 1; else hi = mid; }
  int s = lo;
  lo = s; hi = n;
  while (lo < hi) { int mid = (lo + hi) >> 1; if (gid[mid] < g + 1) lo = mid + 1; else hi = mid; }
  int e = lo;
  int len = e - s;
  if (len <= 0) return;
  int chunk = (len + 7) / 8;
  int cs = s + part * chunk;
  int ce = cs + chunk; if (ce > e) ce = e;
  if (cs >= ce) return;
  float acc = 0.f;
  for (int v = cs; v < ce; v++) acc += bf_lo((unsigned)x3[(size_t)v * 256 + f]);
  atomicAdd(&out[g * 256 + f], acc);
}

// ---------------- launch ----------------

extern "C" void kernel_launch(void* const* d_in, const int* in_sizes, int n_in,
                              void* d_out, int out_size, void* d_ws, size_t ws_size,
                              hipStream_t stream) {
  const float* x     = (const float*)d_in[0];
  const float* w     = (const float*)d_in[1];
  const float* W1    = (const float*)d_in[2];
  const float* Wfc   = (const float*)d_in[3];
  const float* gamma = (const float*)d_in[4];
  const float* beta  = (const float*)d_in[5];
  const float* W2    = (const float*)d_in[6];
  const float* W3    = (const float*)d_in[7];
  const int*   src   = (const int*)d_in[8];
  const int*   dst   = (const int*)d_in[9];
  const int*   gid   = (const int*)d_in[10];
  float* out = (float*)d_out;

  const int N = NN, E = NE;

  char* p = (char*)d_ws;
  auto alloc = [&](size_t bytes) {
    char* r = p;
    p += (bytes + 255) & ~(size_t)255;
    return r;
  };
  unsigned char* hout = (unsigned char*)alloc((size_t)NB_H * N);  // per-chunk out-hist (u8)
  unsigned char* hin  = (unsigned char*)alloc((size_t)NB_H * N);  // per-chunk in-hist -> binBase
  int*   din     = (int*)alloc((size_t)N * 4);
  float* onorm   = (float*)alloc((size_t)N * 4);
  float* inorm   = (float*)alloc((size_t)N * 4);
  int*   row_ptr = (int*)alloc((size_t)(N + 1) * 4);
  int*   bsum    = (int*)alloc(256 * 4);
  int*   rank    = (int*)alloc((size_t)E * 4);
  uint2* edge    = (uint2*)alloc((size_t)E * 8);  // interleaved {col, wse}
  unsigned short* xb    = (unsigned short*)alloc((size_t)N * 128 * 2);
  unsigned short* aggX  = (unsigned short*)alloc((size_t)N * 128 * 2);
  unsigned short* x1f1  = (unsigned short*)alloc((size_t)N * 512 * 2);
  unsigned short* y2    = (unsigned short*)alloc((size_t)N * 256 * 2);
  unsigned short* x2    = (unsigned short*)alloc((size_t)N * 256 * 2);
  unsigned short* aggx2 = (unsigned short*)alloc((size_t)N * 256 * 2);
  unsigned short* W1t   = (unsigned short*)alloc((size_t)256 * 128 * 2);
  unsigned short* Wfct  = (unsigned short*)alloc((size_t)256 * 128 * 2);
  unsigned short* W2t   = (unsigned short*)alloc((size_t)256 * 512 * 2);
  unsigned short* W3t   = (unsigned short*)alloc((size_t)256 * 256 * 2);
  unsigned short* x3 = x1f1;  // x1f1 dead after y2 GEMM; reuse storage

  hipMemsetAsync(out, 0, (size_t)NG * 256 * 4, stream);

  const int nbS = (N + 255) / 256;  // 196

  prep_kernel<<<NB_H + XB + WTB, 1024, 0, stream>>>(src, dst, hout, hin, rank,
                                                    x, xb, W1, Wfc, W2, W3,
                                                    W1t, Wfct, W2t, W3t);
  norms_scan1<<<nbS, 256, 0, stream>>>(hout, hin, din, onorm, inorm, bsum, N);
  scan3_kernel<<<nbS, 256, 0, stream>>>(din, bsum, row_ptr, N, nbS);
  fill_kernel<<<(E + 255) / 256, 256, 0, stream>>>(src, dst, w, onorm, inorm, row_ptr,
                                                   rank, hin, edge, E);

  dim3 ggrid((N + 127) / 128, 2);  // 391 x 2

  // aggX' = agg(xb)
  spmm_bf16<0, 1><<<N, 64, 0, stream>>>(xb, 128, row_ptr, edge, aggX, 128);
  // z=0: x1 = relu(aggX@W1) -> x1f1[:,0:256] ; z=1: f1 = relu(LN(xb@Wfc)) -> x1f1[:,256:512]
  g12f_kernel<<<dim3(782, 1, 2), 256, 0, stream>>>(aggX, W1t, xb, Wfct, gamma, beta, x1f1, N);
  // y2 = x1f1 @ W2
  gemm_kernel<<<ggrid, 256, 0, stream>>>(x1f1, 512, W2t, 512, y2, 256, N, 0);
  // x2 = relu(agg'(y2))
  spmm_bf16<1, 2><<<N, 64, 0, stream>>>(y2, 256, row_ptr, edge, x2, 256);
  // aggx2 = agg'(x2)
  spmm_bf16<0, 2><<<N, 64, 0, stream>>>(x2, 256, row_ptr, edge, aggx2, 256);
  // x3 = relu(aggx2 @ W3)
  gemm_kernel<<<ggrid, 256, 0, stream>>>(aggx2, 256, W3t, 256, x3, 256, N, 1);
  // readout
  readout_kernel<<<dim3(NG, 8), 256, 0, stream>>>(x3, gid, out, N);
}